// Round 4
// baseline (900.439 us; speedup 1.0000x reference)
//
#include <hip/hip_runtime.h>

#define BB 32
#define TT 2048
#define CC 64
#define BT (BB * TT)
#define NCH 16
#define CL 128  // chunk length; NCH*CL == TT
#define GN_EPS (1e-5f * 64.f)

// ---- cross-lane helpers --------------------------------------------------
__device__ __forceinline__ float rl(float v, int lane) {
  return __uint_as_float(__builtin_amdgcn_readlane(__float_as_uint(v), lane));
}
template <int CTRL>
__device__ __forceinline__ float dppadd(float x) {
  return x + __int_as_float(__builtin_amdgcn_update_dpp(
                 0, __float_as_int(x), CTRL, 0xf, 0xf, true));
}
// Full wave64 sum -> broadcast (lane63 holds total, readlane broadcasts).
__device__ __forceinline__ float wave_red_sum(float x) {
  x = dppadd<0x111>(x);  // row_shr:1
  x = dppadd<0x112>(x);  // row_shr:2
  x = dppadd<0x114>(x);  // row_shr:4
  x = dppadd<0x118>(x);  // row_shr:8
  x = dppadd<0x142>(x);  // row_bcast:15
  x = dppadd<0x143>(x);  // row_bcast:31
  return __uint_as_float(__builtin_amdgcn_readlane(__float_as_uint(x), 63));
}
__device__ __forceinline__ float tanh_f(float x) {
  x = fminf(fmaxf(x, -10.f), 10.f);
  const float e = __expf(2.f * x);
  return (e - 1.f) / (e + 1.f);
}

// ---- mix: token-shift + maa mixing -> 5 shifted streams (80KB LDS) -------
__global__ __launch_bounds__(512, 4) void mix_kernel(
    const float* __restrict__ x,
    const float* __restrict__ tm_x, const float* __restrict__ tm_w, const float* __restrict__ tm_k,
    const float* __restrict__ tm_v, const float* __restrict__ tm_r, const float* __restrict__ tm_g,
    const float* __restrict__ maa_w1, const float* __restrict__ maa_w2,
    float* __restrict__ xw_o, float* __restrict__ xk_o, float* __restrict__ xv_o,
    float* __restrict__ xr_o, float* __restrict__ xg_o)
{
  __shared__ float2 w1a[4096];   // {w1[c][j], w1[c][64+j]}         32KB
  __shared__ float  w1c[2048];   // w1[c][128+jj], jj<32             8KB
  __shared__ float4 w2a[2048];   // w2[f=0..3][q][j]                32KB
  __shared__ float  w2b[2048];   // w2[f=4][q][j]                    8KB
  const int tid = threadIdx.x;
  for (int idx = tid; idx < 4096; idx += 512) {
    const int c = idx >> 6, jj = idx & 63;
    w1a[idx] = make_float2(maa_w1[c * 160 + jj], maa_w1[c * 160 + 64 + jj]);
  }
  for (int idx = tid; idx < 2048; idx += 512) {
    const int c = idx >> 5, jj = idx & 31;
    w1c[idx] = maa_w1[c * 160 + 128 + jj];
  }
  for (int idx = tid; idx < 2048; idx += 512) {
    const int q = idx >> 6, jj = idx & 63;
    w2a[idx] = make_float4(maa_w2[q * 64 + jj], maa_w2[(32 + q) * 64 + jj],
                           maa_w2[(64 + q) * 64 + jj], maa_w2[(96 + q) * 64 + jj]);
    w2b[idx] = maa_w2[(128 + q) * 64 + jj];
  }
  __syncthreads();

  const int w = tid >> 6, j = tid & 63;
  const int j32 = j & 31;
  const int bt0 = blockIdx.x * 32 + w * 4;
  const float tmx = tm_x[j], tmw = tm_w[j], tmk = tm_k[j],
              tmv = tm_v[j], tmr = tm_r[j], tmg = tm_g[j];

  float xc[4], xx[4], xxx[4];
#pragma unroll
  for (int q = 0; q < 4; ++q) {
    const int bt = bt0 + q;
    const int t = bt & (TT - 1);
    const float cur = x[(size_t)bt * CC + j];
    const float prv = (t != 0) ? x[(size_t)(bt - 1) * CC + j] : 0.f;
    xc[q] = cur;
    xx[q] = prv - cur;
    xxx[q] = fmaf(xx[q], tmx, cur);
  }

  float a0[4] = {0, 0, 0, 0}, a1[4] = {0, 0, 0, 0}, a2[4] = {0, 0, 0, 0};
#pragma unroll
  for (int c = 0; c < 64; ++c) {
    const float2 wv = w1a[c * 64 + j];
    const float wc = w1c[c * 32 + j32];  // lanes >=32 duplicate lanes 0..31
#pragma unroll
    for (int q = 0; q < 4; ++q) {
      const float s = rl(xxx[q], c);
      a0[q] = fmaf(s, wv.x, a0[q]);
      a1[q] = fmaf(s, wv.y, a1[q]);
      a2[q] = fmaf(s, wc, a2[q]);
    }
  }
#pragma unroll
  for (int q = 0; q < 4; ++q) {
    a0[q] = tanh_f(a0[q]); a1[q] = tanh_f(a1[q]); a2[q] = tanh_f(a2[q]);
  }

  float m0[4] = {0,0,0,0}, m1[4] = {0,0,0,0}, m2[4] = {0,0,0,0},
        m3[4] = {0,0,0,0}, m4[4] = {0,0,0,0};
#pragma unroll
  for (int q2 = 0; q2 < 32; ++q2) {
    const float4 w4 = w2a[q2 * 64 + j];
    const float w5 = w2b[q2 * 64 + j];
#pragma unroll
    for (int q = 0; q < 4; ++q) {
      m0[q] = fmaf(rl(a0[q], q2),      w4.x, m0[q]);
      m1[q] = fmaf(rl(a0[q], 32 + q2), w4.y, m1[q]);
      m2[q] = fmaf(rl(a1[q], q2),      w4.z, m2[q]);
      m3[q] = fmaf(rl(a1[q], 32 + q2), w4.w, m3[q]);
      m4[q] = fmaf(rl(a2[q], q2),      w5,   m4[q]);
    }
  }
#pragma unroll
  for (int q = 0; q < 4; ++q) {
    const size_t o = (size_t)(bt0 + q) * CC + j;
    xw_o[o] = fmaf(xx[q], tmw + m0[q], xc[q]);
    xk_o[o] = fmaf(xx[q], tmk + m1[q], xc[q]);
    xv_o[o] = fmaf(xx[q], tmv + m2[q], xc[q]);
    xr_o[o] = fmaf(xx[q], tmr + m3[q], xc[q]);
    xg_o[o] = fmaf(xx[q], tmg + m4[q], xc[q]);
  }
}

// ---- proj4: r,k,v,g projections + ct; packs rkdc.{x,y,w}, vT, g ----------
__global__ __launch_bounds__(512, 4) void proj4_kernel(
    const float* __restrict__ xk_i, const float* __restrict__ xv_i,
    const float* __restrict__ xr_i, const float* __restrict__ xg_i,
    const float* __restrict__ u,
    const float* __restrict__ Wr, const float* __restrict__ Wk, const float* __restrict__ Wv,
    const float* __restrict__ Wg,
    float* __restrict__ rkdc, float* __restrict__ vT, float* __restrict__ g_o)
{
  __shared__ float4 projW[4096];   // {Wr^T, Wk^T, Wv^T, Wg^T}[c][j]   64KB
  __shared__ float vbuf[64][33];   // v transpose staging              8.4KB
  const int tid = threadIdx.x;
  for (int idx = tid; idx < 4096; idx += 512) {
    const int c = idx >> 6, jj = idx & 63;
    projW[idx] = make_float4(Wr[jj * 64 + c], Wk[jj * 64 + c],
                             Wv[jj * 64 + c], Wg[jj * 64 + c]);
  }
  __syncthreads();

  const int w = tid >> 6, j = tid & 63;
  const int bt0 = blockIdx.x * 32 + w * 4;
  const float u_j = u[j];

  float xk[4], xv_[4], xr[4], xg[4];
#pragma unroll
  for (int q = 0; q < 4; ++q) {
    const size_t o = (size_t)(bt0 + q) * CC + j;
    xk[q] = xk_i[o]; xv_[q] = xv_i[o]; xr[q] = xr_i[o]; xg[q] = xg_i[o];
  }

  float ar[4] = {0,0,0,0}, ak[4] = {0,0,0,0}, av[4] = {0,0,0,0}, ag[4] = {0,0,0,0};
#pragma unroll
  for (int c = 0; c < 64; ++c) {
    const float4 wv = projW[c * 64 + j];
#pragma unroll
    for (int q = 0; q < 4; ++q) {
      ar[q] = fmaf(rl(xr[q], c),  wv.x, ar[q]);
      ak[q] = fmaf(rl(xk[q], c),  wv.y, ak[q]);
      av[q] = fmaf(rl(xv_[q], c), wv.z, av[q]);
      ag[q] = fmaf(rl(xg[q], c),  wv.w, ag[q]);
    }
  }

#pragma unroll
  for (int q = 0; q < 4; ++q) {
    const size_t o = (size_t)(bt0 + q) * CC + j;
    const float ct = wave_red_sum(ar[q] * u_j * ak[q]);  // sum_i r_i u_i k_i
    rkdc[4 * o + 0] = ar[q];
    rkdc[4 * o + 1] = ak[q];
    rkdc[4 * o + 3] = ct;
    g_o[o] = ag[q] / (1.f + __expf(-ag[q]));  // silu
    vbuf[j][w * 4 + q] = av[q];
  }
  __syncthreads();
  // v transpose: vT[b][j][t], coalesced store
  const int b = blockIdx.x >> 6;
  const int tblk = (blockIdx.x & 63) * 32;
  for (int idx = tid; idx < 2048; idx += 512) {
    const int jj = idx >> 5, tt = idx & 31;
    vT[((size_t)b * CC + jj) * TT + tblk + tt] = vbuf[jj][tt];
  }
}

// ---- dec: decay MLP -> rkdc.z --------------------------------------------
__global__ __launch_bounds__(512, 4) void dec_kernel(
    const float* __restrict__ xw_i, const float* __restrict__ t_decay,
    const float* __restrict__ dec_w1, const float* __restrict__ dec_w2,
    float* __restrict__ rkdc)
{
  __shared__ float2 decW[4096];  // {dec_w1[c][j], dec_w2[c][j]}  32KB
  const int tid = threadIdx.x;
  for (int idx = tid; idx < 4096; idx += 512)
    decW[idx] = make_float2(dec_w1[idx], dec_w2[idx]);
  __syncthreads();

  const int w = tid >> 6, j = tid & 63;
  const int bt0 = blockIdx.x * 32 + w * 4;
  const float td = t_decay[j];

  float xw[4];
#pragma unroll
  for (int q = 0; q < 4; ++q) xw[q] = xw_i[(size_t)(bt0 + q) * CC + j];

  float hh[4] = {0,0,0,0};
#pragma unroll
  for (int c = 0; c < 64; ++c) {
    const float dw = decW[c * 64 + j].x;
#pragma unroll
    for (int q = 0; q < 4; ++q) hh[q] = fmaf(rl(xw[q], c), dw, hh[q]);
  }
#pragma unroll
  for (int q = 0; q < 4; ++q) hh[q] = tanh_f(hh[q]);

  float wf[4] = {td, td, td, td};
#pragma unroll
  for (int c = 0; c < 64; ++c) {
    const float dw = decW[c * 64 + j].y;
#pragma unroll
    for (int q = 0; q < 4; ++q) wf[q] = fmaf(rl(hh[q], c), dw, wf[q]);
  }
#pragma unroll
  for (int q = 0; q < 4; ++q)
    rkdc[4 * ((size_t)(bt0 + q) * CC + j) + 2] = __expf(-__expf(wf[q]));
}

// ---- A: chunk-local scan (no y): Sloc = chunk final state, Dp = prod d ---
__global__ __launch_bounds__(256, 8) void chunk_local_kernel(
    const float4* __restrict__ rkdc, const float* __restrict__ vT,
    float* __restrict__ Sloc, float* __restrict__ Dp)
{
  const int blk = blockIdx.x;
  const int jg = blk & 15;
  const int bch = blk >> 4;            // b*NCH + ch
  const int ch = bch & (NCH - 1);
  const int b = bch >> 4;              // NCH==16
  const int w = threadIdx.x >> 6, i = threadIdx.x & 63;
  const int j = jg * 4 + w;
  const float4* fp = rkdc + ((size_t)(b * TT + ch * CL)) * CC + i;
  const float* vp = vT + ((size_t)(b * CC + j)) * TT + ch * CL;

  float S = 0.f, dp = 1.f;
  float4 f0 = fp[0 * CC], f1 = fp[1 * CC], f2 = fp[2 * CC], f3 = fp[3 * CC];
  float4 vvc = *reinterpret_cast<const float4*>(vp);
  for (int t = 0; t < CL; t += 4) {
    const int tv = (t + 4 < CL) ? t + 4 : CL - 4;
    const float4 vvn = *reinterpret_cast<const float4*>(vp + tv);
    S = fmaf(S, f0.z, f0.y * vvc.x); dp *= f0.z;
    { int tn = t + 4; if (tn > CL - 1) tn = CL - 1; f0 = fp[(size_t)tn * CC]; }
    S = fmaf(S, f1.z, f1.y * vvc.y); dp *= f1.z;
    { int tn = t + 5; if (tn > CL - 1) tn = CL - 1; f1 = fp[(size_t)tn * CC]; }
    S = fmaf(S, f2.z, f2.y * vvc.z); dp *= f2.z;
    { int tn = t + 6; if (tn > CL - 1) tn = CL - 1; f2 = fp[(size_t)tn * CC]; }
    S = fmaf(S, f3.z, f3.y * vvc.w); dp *= f3.z;
    { int tn = t + 7; if (tn > CL - 1) tn = CL - 1; f3 = fp[(size_t)tn * CC]; }
    vvc = vvn;
  }
  Sloc[((size_t)bch * CC + j) * CC + i] = S;
  if (j == 0) Dp[(size_t)bch * CC + i] = dp;
}

// ---- B: inter-chunk combine: S0[ch] = initial state for chunk ch ---------
__global__ __launch_bounds__(512) void combine_kernel(
    const float* __restrict__ Sloc, const float* __restrict__ Dp, float* __restrict__ S0)
{
  const int b = blockIdx.x, tid = threadIdx.x;
  __shared__ float sDp[NCH * CC];
  for (int idx = tid; idx < NCH * CC; idx += 512)
    sDp[idx] = Dp[(size_t)b * NCH * CC + idx];
  __syncthreads();
  float run[8];
#pragma unroll
  for (int k2 = 0; k2 < 8; ++k2) run[k2] = 0.f;
  for (int ch = 0; ch < NCH; ++ch) {
    const size_t base = ((size_t)(b * NCH + ch)) * (CC * CC);
#pragma unroll
    for (int k2 = 0; k2 < 8; ++k2) {
      const int idx = tid + k2 * 512;
      const float tmp = Sloc[base + idx];
      S0[base + idx] = run[k2];
      run[k2] = fmaf(run[k2], sDp[ch * CC + (idx & 63)], tmp);
    }
  }
}

// ---- C: emit scan with correct initial state -----------------------------
__global__ __launch_bounds__(256, 8) void scan_emit_kernel(
    const float4* __restrict__ rkdc, const float* __restrict__ vT,
    const float* __restrict__ S0, float* __restrict__ yb)
{
  const int blk = blockIdx.x;
  const int jg = blk & 15;
  const int bch = blk >> 4;
  const int ch = bch & (NCH - 1);
  const int b = bch >> 4;
  const int w = threadIdx.x >> 6, i = threadIdx.x & 63;
  const int j = jg * 4 + w;
  const float4* fp = rkdc + ((size_t)(b * TT + ch * CL)) * CC + i;
  const float* vp = vT + ((size_t)(b * CC + j)) * TT + ch * CL;
  float* yp = yb + ((size_t)(b * TT + ch * CL)) * CC + j;

  float S = S0[((size_t)bch * CC + j) * CC + i];
  float4 f0 = fp[0 * CC], f1 = fp[1 * CC], f2 = fp[2 * CC], f3 = fp[3 * CC];
  float4 vvc = *reinterpret_cast<const float4*>(vp);

  for (int t = 0; t < CL; t += 4) {
    const int tv = (t + 4 < CL) ? t + 4 : CL - 4;
    const float4 vvn = *reinterpret_cast<const float4*>(vp + tv);
    {
      const float p = wave_red_sum(f0.x * S);
      S = fmaf(S, f0.z, f0.y * vvc.x);
      if (i == 0) yp[(size_t)t * CC] = fmaf(f0.w, vvc.x, p);
      int tn = t + 4; if (tn > CL - 1) tn = CL - 1;
      f0 = fp[(size_t)tn * CC];
    }
    {
      const float p = wave_red_sum(f1.x * S);
      S = fmaf(S, f1.z, f1.y * vvc.y);
      if (i == 0) yp[(size_t)(t + 1) * CC] = fmaf(f1.w, vvc.y, p);
      int tn = t + 5; if (tn > CL - 1) tn = CL - 1;
      f1 = fp[(size_t)tn * CC];
    }
    {
      const float p = wave_red_sum(f2.x * S);
      S = fmaf(S, f2.z, f2.y * vvc.z);
      if (i == 0) yp[(size_t)(t + 2) * CC] = fmaf(f2.w, vvc.z, p);
      int tn = t + 6; if (tn > CL - 1) tn = CL - 1;
      f2 = fp[(size_t)tn * CC];
    }
    {
      const float p = wave_red_sum(f3.x * S);
      S = fmaf(S, f3.z, f3.y * vvc.w);
      if (i == 0) yp[(size_t)(t + 3) * CC] = fmaf(f3.w, vvc.w, p);
      int tn = t + 7; if (tn > CL - 1) tn = CL - 1;
      f3 = fp[(size_t)tn * CC];
    }
    vvc = vvn;
  }
}

// ---- post: GroupNorm(64) + *g + @Wo.T, in place on d_out -----------------
__global__ __launch_bounds__(512, 4) void post_kernel(
    const float* __restrict__ g_i, const float* __restrict__ ln_w, const float* __restrict__ ln_b,
    const float* __restrict__ Wo, float* __restrict__ out)
{
  __shared__ float WoT[4096];  // Wo^T[c][j]  16KB
  const int tid = threadIdx.x;
  for (int idx = tid; idx < 4096; idx += 512) {
    const int c = idx >> 6, jj = idx & 63;
    WoT[idx] = Wo[jj * 64 + c];
  }
  __syncthreads();
  const int w = tid >> 6, j = tid & 63;
  const int bt0 = blockIdx.x * 32 + w * 4;
  const float lnw = ln_w[j], lnb = ln_b[j];
  float sz[4];
#pragma unroll
  for (int q = 0; q < 4; ++q) {
    const size_t o = (size_t)(bt0 + q) * CC + j;
    const float y = out[o];
    const float s1 = wave_red_sum(y);
    const float s2 = wave_red_sum(y * y);
    const float mu = s1 * (1.f / CC);
    const float var = s2 * (1.f / CC) - mu * mu;
    const float z = (y - mu) * rsqrtf(var + GN_EPS) * lnw + lnb;
    sz[q] = z * g_i[o];
  }
  float acc[4] = {0, 0, 0, 0};
#pragma unroll
  for (int c = 0; c < 64; ++c) {
    const float wv = WoT[c * 64 + j];
#pragma unroll
    for (int q = 0; q < 4; ++q) acc[q] = fmaf(rl(sz[q], c), wv, acc[q]);
  }
#pragma unroll
  for (int q = 0; q < 4; ++q) out[(size_t)(bt0 + q) * CC + j] = acc[q];
}

extern "C" void kernel_launch(void* const* d_in, const int* in_sizes, int n_in,
                              void* d_out, int out_size, void* d_ws, size_t ws_size,
                              hipStream_t stream) {
  const float* x       = (const float*)d_in[0];
  const float* tm_x    = (const float*)d_in[1];
  const float* tm_w    = (const float*)d_in[2];
  const float* tm_k    = (const float*)d_in[3];
  const float* tm_v    = (const float*)d_in[4];
  const float* tm_r    = (const float*)d_in[5];
  const float* tm_g    = (const float*)d_in[6];
  const float* maa_w1  = (const float*)d_in[7];
  const float* maa_w2  = (const float*)d_in[8];
  const float* t_decay = (const float*)d_in[9];
  const float* dec_w1  = (const float*)d_in[10];
  const float* dec_w2  = (const float*)d_in[11];
  const float* u       = (const float*)d_in[12];
  const float* Wr      = (const float*)d_in[13];
  const float* Wk      = (const float*)d_in[14];
  const float* Wv      = (const float*)d_in[15];
  const float* Wg      = (const float*)d_in[16];
  const float* Wo      = (const float*)d_in[17];
  const float* ln_w    = (const float*)d_in[18];
  const float* ln_b    = (const float*)d_in[19];

  const size_t M = (size_t)BT * CC;
  float* ws   = (float*)d_ws;
  float* xk_o = ws;              // dead after proj4 -> reused as Sloc
  float* xv_o = ws + M;          // dead after proj4 -> reused as S0
  float* xr_o = ws + 2 * M;      // dead after proj4 -> reused as Dp
  float* xg_o = ws + 3 * M;
  float* g_o  = ws + 4 * M;
  float* vT   = ws + 5 * M;
  float* rkdc = ws + 6 * M;      // float4 stream, [6M,10M)
  float* Sloc = ws;              // B*NCH*64*64
  float* S0b  = ws + M;
  float* Dp   = ws + 2 * M;
  float* out  = (float*)d_out;   // xw stream -> y -> final

  mix_kernel<<<2048, 512, 0, stream>>>(
      x, tm_x, tm_w, tm_k, tm_v, tm_r, tm_g, maa_w1, maa_w2,
      out /* xw */, xk_o, xv_o, xr_o, xg_o);

  proj4_kernel<<<2048, 512, 0, stream>>>(
      xk_o, xv_o, xr_o, xg_o, u, Wr, Wk, Wv, Wg, rkdc, vT, g_o);

  dec_kernel<<<2048, 512, 0, stream>>>(out /* xw */, t_decay, dec_w1, dec_w2, rkdc);

  chunk_local_kernel<<<BB * NCH * 16, 256, 0, stream>>>(
      (const float4*)rkdc, vT, Sloc, Dp);

  combine_kernel<<<BB, 512, 0, stream>>>(Sloc, Dp, S0b);

  scan_emit_kernel<<<BB * NCH * 16, 256, 0, stream>>>(
      (const float4*)rkdc, vT, S0b, out /* y */);

  post_kernel<<<2048, 512, 0, stream>>>(g_o, ln_w, ln_b, Wo, out);
}

// Round 5
// 462.469 us; speedup vs baseline: 1.9470x; 1.9470x over previous
//
#include <hip/hip_runtime.h>

#define BB 32
#define TT 2048
#define CC 64
#define BT (BB * TT)
#define NCH 64
#define CL 32  // chunk length; NCH*CL == TT
#define GN_EPS (1e-5f * 64.f)

// ---- cross-lane helpers --------------------------------------------------
__device__ __forceinline__ float rl(float v, int lane) {
  return __uint_as_float(__builtin_amdgcn_readlane(__float_as_uint(v), lane));
}
template <int CTRL>
__device__ __forceinline__ float dppadd(float x) {
  return x + __int_as_float(__builtin_amdgcn_update_dpp(
                 0, __float_as_int(x), CTRL, 0xf, 0xf, true));
}
// Full wave64 sum -> broadcast.
__device__ __forceinline__ float wave_red_sum(float x) {
  x = dppadd<0x111>(x);  // row_shr:1
  x = dppadd<0x112>(x);  // row_shr:2
  x = dppadd<0x114>(x);  // row_shr:4
  x = dppadd<0x118>(x);  // row_shr:8
  x = dppadd<0x142>(x);  // row_bcast:15
  x = dppadd<0x143>(x);  // row_bcast:31
  return __uint_as_float(__builtin_amdgcn_readlane(__float_as_uint(x), 63));
}
__device__ __forceinline__ float tanh_f(float x) {
  x = fminf(fmaxf(x, -10.f), 10.f);
  const float e = __expf(2.f * x);
  return (e - 1.f) / (e + 1.f);
}

// ---- mix: token-shift + maa mixing -> 5 shifted streams ------------------
__global__ __launch_bounds__(512, 4) void mix_kernel(
    const float* __restrict__ x,
    const float* __restrict__ tm_x, const float* __restrict__ tm_w, const float* __restrict__ tm_k,
    const float* __restrict__ tm_v, const float* __restrict__ tm_r, const float* __restrict__ tm_g,
    const float* __restrict__ maa_w1, const float* __restrict__ maa_w2,
    float* __restrict__ xw_o, float* __restrict__ xk_o, float* __restrict__ xv_o,
    float* __restrict__ xr_o, float* __restrict__ xg_o)
{
  __shared__ float2 w1a[4096];
  __shared__ float  w1c[2048];
  __shared__ float4 w2a[2048];
  __shared__ float  w2b[2048];
  const int tid = threadIdx.x;
  for (int idx = tid; idx < 4096; idx += 512) {
    const int c = idx >> 6, jj = idx & 63;
    w1a[idx] = make_float2(maa_w1[c * 160 + jj], maa_w1[c * 160 + 64 + jj]);
  }
  for (int idx = tid; idx < 2048; idx += 512) {
    const int c = idx >> 5, jj = idx & 31;
    w1c[idx] = maa_w1[c * 160 + 128 + jj];
  }
  for (int idx = tid; idx < 2048; idx += 512) {
    const int q = idx >> 6, jj = idx & 63;
    w2a[idx] = make_float4(maa_w2[q * 64 + jj], maa_w2[(32 + q) * 64 + jj],
                           maa_w2[(64 + q) * 64 + jj], maa_w2[(96 + q) * 64 + jj]);
    w2b[idx] = maa_w2[(128 + q) * 64 + jj];
  }
  __syncthreads();

  const int w = tid >> 6, j = tid & 63;
  const int j32 = j & 31;
  const int bt0 = blockIdx.x * 32 + w * 4;
  const float tmx = tm_x[j], tmw = tm_w[j], tmk = tm_k[j],
              tmv = tm_v[j], tmr = tm_r[j], tmg = tm_g[j];

  float xc[4], xx[4], xxx[4];
#pragma unroll
  for (int q = 0; q < 4; ++q) {
    const int bt = bt0 + q;
    const int t = bt & (TT - 1);
    const float cur = x[(size_t)bt * CC + j];
    const float prv = (t != 0) ? x[(size_t)(bt - 1) * CC + j] : 0.f;
    xc[q] = cur;
    xx[q] = prv - cur;
    xxx[q] = fmaf(xx[q], tmx, cur);
  }

  float a0[4] = {0, 0, 0, 0}, a1[4] = {0, 0, 0, 0}, a2[4] = {0, 0, 0, 0};
#pragma unroll
  for (int c = 0; c < 64; ++c) {
    const float2 wv = w1a[c * 64 + j];
    const float wc = w1c[c * 32 + j32];
#pragma unroll
    for (int q = 0; q < 4; ++q) {
      const float s = rl(xxx[q], c);
      a0[q] = fmaf(s, wv.x, a0[q]);
      a1[q] = fmaf(s, wv.y, a1[q]);
      a2[q] = fmaf(s, wc, a2[q]);
    }
  }
#pragma unroll
  for (int q = 0; q < 4; ++q) {
    a0[q] = tanh_f(a0[q]); a1[q] = tanh_f(a1[q]); a2[q] = tanh_f(a2[q]);
  }

  float m0[4] = {0,0,0,0}, m1[4] = {0,0,0,0}, m2[4] = {0,0,0,0},
        m3[4] = {0,0,0,0}, m4[4] = {0,0,0,0};
#pragma unroll
  for (int q2 = 0; q2 < 32; ++q2) {
    const float4 w4 = w2a[q2 * 64 + j];
    const float w5 = w2b[q2 * 64 + j];
#pragma unroll
    for (int q = 0; q < 4; ++q) {
      m0[q] = fmaf(rl(a0[q], q2),      w4.x, m0[q]);
      m1[q] = fmaf(rl(a0[q], 32 + q2), w4.y, m1[q]);
      m2[q] = fmaf(rl(a1[q], q2),      w4.z, m2[q]);
      m3[q] = fmaf(rl(a1[q], 32 + q2), w4.w, m3[q]);
      m4[q] = fmaf(rl(a2[q], q2),      w5,   m4[q]);
    }
  }
#pragma unroll
  for (int q = 0; q < 4; ++q) {
    const size_t o = (size_t)(bt0 + q) * CC + j;
    xw_o[o] = fmaf(xx[q], tmw + m0[q], xc[q]);
    xk_o[o] = fmaf(xx[q], tmk + m1[q], xc[q]);
    xv_o[o] = fmaf(xx[q], tmv + m2[q], xc[q]);
    xr_o[o] = fmaf(xx[q], tmr + m3[q], xc[q]);
    xg_o[o] = fmaf(xx[q], tmg + m4[q], xc[q]);
  }
}

// ---- proj4: r,k,v,g projections + ct -------------------------------------
__global__ __launch_bounds__(512, 4) void proj4_kernel(
    const float* __restrict__ xk_i, const float* __restrict__ xv_i,
    const float* __restrict__ xr_i, const float* __restrict__ xg_i,
    const float* __restrict__ u,
    const float* __restrict__ Wr, const float* __restrict__ Wk, const float* __restrict__ Wv,
    const float* __restrict__ Wg,
    float* __restrict__ rkdc, float* __restrict__ v_o, float* __restrict__ g_o)
{
  __shared__ float4 projW[4096];   // {Wr^T, Wk^T, Wv^T, Wg^T}[c][j]
  const int tid = threadIdx.x;
  for (int idx = tid; idx < 4096; idx += 512) {
    const int c = idx >> 6, jj = idx & 63;
    projW[idx] = make_float4(Wr[jj * 64 + c], Wk[jj * 64 + c],
                             Wv[jj * 64 + c], Wg[jj * 64 + c]);
  }
  __syncthreads();

  const int w = tid >> 6, j = tid & 63;
  const int bt0 = blockIdx.x * 32 + w * 4;
  const float u_j = u[j];

  float xk[4], xv_[4], xr[4], xg[4];
#pragma unroll
  for (int q = 0; q < 4; ++q) {
    const size_t o = (size_t)(bt0 + q) * CC + j;
    xk[q] = xk_i[o]; xv_[q] = xv_i[o]; xr[q] = xr_i[o]; xg[q] = xg_i[o];
  }

  float ar[4] = {0,0,0,0}, ak[4] = {0,0,0,0}, av[4] = {0,0,0,0}, ag[4] = {0,0,0,0};
#pragma unroll
  for (int c = 0; c < 64; ++c) {
    const float4 wv = projW[c * 64 + j];
#pragma unroll
    for (int q = 0; q < 4; ++q) {
      ar[q] = fmaf(rl(xr[q], c),  wv.x, ar[q]);
      ak[q] = fmaf(rl(xk[q], c),  wv.y, ak[q]);
      av[q] = fmaf(rl(xv_[q], c), wv.z, av[q]);
      ag[q] = fmaf(rl(xg[q], c),  wv.w, ag[q]);
    }
  }

#pragma unroll
  for (int q = 0; q < 4; ++q) {
    const size_t o = (size_t)(bt0 + q) * CC + j;
    const float ct = wave_red_sum(ar[q] * u_j * ak[q]);  // sum_i r_i u_i k_i
    rkdc[4 * o + 0] = ar[q];
    rkdc[4 * o + 1] = ak[q];
    rkdc[4 * o + 3] = ct;
    v_o[o] = av[q];
    g_o[o] = ag[q] / (1.f + __expf(-ag[q]));  // silu
  }
}

// ---- dec: decay MLP -> rkdc.z --------------------------------------------
__global__ __launch_bounds__(512, 4) void dec_kernel(
    const float* __restrict__ xw_i, const float* __restrict__ t_decay,
    const float* __restrict__ dec_w1, const float* __restrict__ dec_w2,
    float* __restrict__ rkdc)
{
  __shared__ float2 decW[4096];  // {dec_w1[c][j], dec_w2[c][j]}
  const int tid = threadIdx.x;
  for (int idx = tid; idx < 4096; idx += 512)
    decW[idx] = make_float2(dec_w1[idx], dec_w2[idx]);
  __syncthreads();

  const int w = tid >> 6, j = tid & 63;
  const int bt0 = blockIdx.x * 32 + w * 4;
  const float td = t_decay[j];

  float xw[4];
#pragma unroll
  for (int q = 0; q < 4; ++q) xw[q] = xw_i[(size_t)(bt0 + q) * CC + j];

  float hh[4] = {0,0,0,0};
#pragma unroll
  for (int c = 0; c < 64; ++c) {
    const float dw = decW[c * 64 + j].x;
#pragma unroll
    for (int q = 0; q < 4; ++q) hh[q] = fmaf(rl(xw[q], c), dw, hh[q]);
  }
#pragma unroll
  for (int q = 0; q < 4; ++q) hh[q] = tanh_f(hh[q]);

  float wf[4] = {td, td, td, td};
#pragma unroll
  for (int c = 0; c < 64; ++c) {
    const float dw = decW[c * 64 + j].y;
#pragma unroll
    for (int q = 0; q < 4; ++q) wf[q] = fmaf(rl(hh[q], c), dw, wf[q]);
  }
#pragma unroll
  for (int q = 0; q < 4; ++q)
    rkdc[4 * ((size_t)(bt0 + q) * CC + j) + 2] = __expf(-__expf(wf[q]));
}

// ---- A: chunk-local state. Wave = (b,ch); lane = j; S[i] in 64 VGPRs. ----
// r/k/d are wave-uniform per (t,i) -> scalar loads; v_j coalesced per lane.
__global__ __launch_bounds__(256) void chunkA_kernel(
    const float4* __restrict__ rkdc, const float* __restrict__ v_i,
    float* __restrict__ Sloc, float* __restrict__ Dp)
{
  const int lane = threadIdx.x & 63;
  const int bch = __builtin_amdgcn_readfirstlane((blockIdx.x << 2) + (threadIdx.x >> 6));
  const float4* fq = rkdc + (size_t)bch * (CL * CC);       // [t][i]
  const float* dq = (const float*)fq + 4 * lane + 2;       // own d (i = lane)
  const float* vq = v_i + (size_t)bch * (CL * CC) + lane;  // v[t][j=lane]

  float S[CC];
#pragma unroll
  for (int i = 0; i < CC; ++i) S[i] = 0.f;
  float dp = 1.f;

  for (int t = 0; t < CL; ++t) {
    const float4* ft = fq + t * CC;
    const float vv = vq[t * CC];
    dp *= dq[4 * t * CC];
#pragma unroll
    for (int i = 0; i < CC; ++i) {
      const float4 f = ft[i];  // uniform address -> s_load
      S[i] = fmaf(f.z, S[i], f.y * vv);
    }
  }
  float* so = Sloc + (size_t)bch * (CC * CC) + lane;
#pragma unroll
  for (int i = 0; i < CC; ++i) so[i * CC] = S[i];
  Dp[(size_t)bch * CC + lane] = dp;
}

// ---- B: in-place combine over chunks: buf[bch] := S0 for that chunk ------
__global__ __launch_bounds__(1024) void combine_kernel(
    float* __restrict__ buf, const float* __restrict__ Dp)
{
  const int b = blockIdx.x, tid = threadIdx.x;
  __shared__ float sDp[NCH * CC];
  for (int idx = tid; idx < NCH * CC; idx += 1024)
    sDp[idx] = Dp[(size_t)b * NCH * CC + idx];
  __syncthreads();
  float run[4] = {0.f, 0.f, 0.f, 0.f};
  for (int ch = 0; ch < NCH; ++ch) {
    const size_t base = ((size_t)(b * NCH + ch)) * (CC * CC);
    const float* drow = sDp + ch * CC;
#pragma unroll
    for (int k2 = 0; k2 < 4; ++k2) {
      const int idx = tid + (k2 << 10);
      const float tmp = buf[base + idx];
      buf[base + idx] = run[k2];
      run[k2] = fmaf(run[k2], drow[idx >> 6], tmp);
    }
  }
}

// ---- C: emit pass with correct initial state -----------------------------
__global__ __launch_bounds__(256) void scanC_kernel(
    const float4* __restrict__ rkdc, const float* __restrict__ v_i,
    const float* __restrict__ S0, float* __restrict__ yb)
{
  const int lane = threadIdx.x & 63;
  const int bch = __builtin_amdgcn_readfirstlane((blockIdx.x << 2) + (threadIdx.x >> 6));
  const float4* fq = rkdc + (size_t)bch * (CL * CC);
  const float* vq = v_i + (size_t)bch * (CL * CC) + lane;
  float* yq = yb + (size_t)bch * (CL * CC) + lane;

  float S[CC];
  const float* si = S0 + (size_t)bch * (CC * CC) + lane;
#pragma unroll
  for (int i = 0; i < CC; ++i) S[i] = si[i * CC];

  for (int t = 0; t < CL; ++t) {
    const float4* ft = fq + t * CC;
    const float vv = vq[t * CC];
    float y0, y1;
    {
      const float4 f = ft[0];
      y0 = fmaf(f.x, S[0], f.w * vv);  // f.w = ct (uniform), y uses OLD S
      S[0] = fmaf(f.z, S[0], f.y * vv);
    }
    {
      const float4 f = ft[1];
      y1 = f.x * S[1];
      S[1] = fmaf(f.z, S[1], f.y * vv);
    }
#pragma unroll
    for (int i = 2; i < CC; i += 2) {
      const float4 fa = ft[i];
      y0 = fmaf(fa.x, S[i], y0);
      S[i] = fmaf(fa.z, S[i], fa.y * vv);
      const float4 fb = ft[i + 1];
      y1 = fmaf(fb.x, S[i + 1], y1);
      S[i + 1] = fmaf(fb.z, S[i + 1], fb.y * vv);
    }
    yq[t * CC] = y0 + y1;
  }
}

// ---- post: GroupNorm(64) + *g + @Wo.T, in place on d_out -----------------
__global__ __launch_bounds__(512, 4) void post_kernel(
    const float* __restrict__ g_i, const float* __restrict__ ln_w, const float* __restrict__ ln_b,
    const float* __restrict__ Wo, float* __restrict__ out)
{
  __shared__ float WoT[4096];  // Wo^T[c][j]
  const int tid = threadIdx.x;
  for (int idx = tid; idx < 4096; idx += 512) {
    const int c = idx >> 6, jj = idx & 63;
    WoT[idx] = Wo[jj * 64 + c];
  }
  __syncthreads();
  const int w = tid >> 6, j = tid & 63;
  const int bt0 = blockIdx.x * 32 + w * 4;
  const float lnw = ln_w[j], lnb = ln_b[j];
  float sz[4];
#pragma unroll
  for (int q = 0; q < 4; ++q) {
    const size_t o = (size_t)(bt0 + q) * CC + j;
    const float y = out[o];
    const float s1 = wave_red_sum(y);
    const float s2 = wave_red_sum(y * y);
    const float mu = s1 * (1.f / CC);
    const float var = s2 * (1.f / CC) - mu * mu;
    const float z = (y - mu) * rsqrtf(var + GN_EPS) * lnw + lnb;
    sz[q] = z * g_i[o];
  }
  float acc[4] = {0, 0, 0, 0};
#pragma unroll
  for (int c = 0; c < 64; ++c) {
    const float wv = WoT[c * 64 + j];
#pragma unroll
    for (int q = 0; q < 4; ++q) acc[q] = fmaf(rl(sz[q], c), wv, acc[q]);
  }
#pragma unroll
  for (int q = 0; q < 4; ++q) out[(size_t)(bt0 + q) * CC + j] = acc[q];
}

extern "C" void kernel_launch(void* const* d_in, const int* in_sizes, int n_in,
                              void* d_out, int out_size, void* d_ws, size_t ws_size,
                              hipStream_t stream) {
  const float* x       = (const float*)d_in[0];
  const float* tm_x    = (const float*)d_in[1];
  const float* tm_w    = (const float*)d_in[2];
  const float* tm_k    = (const float*)d_in[3];
  const float* tm_v    = (const float*)d_in[4];
  const float* tm_r    = (const float*)d_in[5];
  const float* tm_g    = (const float*)d_in[6];
  const float* maa_w1  = (const float*)d_in[7];
  const float* maa_w2  = (const float*)d_in[8];
  const float* t_decay = (const float*)d_in[9];
  const float* dec_w1  = (const float*)d_in[10];
  const float* dec_w2  = (const float*)d_in[11];
  const float* u       = (const float*)d_in[12];
  const float* Wr      = (const float*)d_in[13];
  const float* Wk      = (const float*)d_in[14];
  const float* Wv      = (const float*)d_in[15];
  const float* Wg      = (const float*)d_in[16];
  const float* Wo      = (const float*)d_in[17];
  const float* ln_w    = (const float*)d_in[18];
  const float* ln_b    = (const float*)d_in[19];

  const size_t M = (size_t)BT * CC;  // 4.19M floats
  float* ws   = (float*)d_ws;
  float* xk_o = ws;                  // dead after proj4 -> Sloc/S0 reuse
  float* xv_o = ws + M;              //   "
  float* xr_o = ws + 2 * M;          // dead after proj4 -> Dp reuse
  float* xg_o = ws + 3 * M;
  float* g_o  = ws + 4 * M;          // alive until post
  float* v_o  = ws + 5 * M;          // alive until scanC
  float* rkdc = ws + 6 * M;          // [6M,10M) float4 stream
  float* scb  = ws;                  // Sloc==S0 (in-place), 2M floats
  float* Dp   = ws + 2 * M;          // B*NCH*CC floats
  float* out  = (float*)d_out;       // xw stream -> y -> final

  mix_kernel<<<2048, 512, 0, stream>>>(
      x, tm_x, tm_w, tm_k, tm_v, tm_r, tm_g, maa_w1, maa_w2,
      out /* xw */, xk_o, xv_o, xr_o, xg_o);

  proj4_kernel<<<2048, 512, 0, stream>>>(
      xk_o, xv_o, xr_o, xg_o, u, Wr, Wk, Wv, Wg, rkdc, v_o, g_o);

  dec_kernel<<<2048, 512, 0, stream>>>(out /* xw */, t_decay, dec_w1, dec_w2, rkdc);

  chunkA_kernel<<<(BB * NCH) / 4, 256, 0, stream>>>(
      (const float4*)rkdc, v_o, scb, Dp);

  combine_kernel<<<BB, 1024, 0, stream>>>(scb, Dp);

  scanC_kernel<<<(BB * NCH) / 4, 256, 0, stream>>>(
      (const float4*)rkdc, v_o, scb, out /* y */);

  post_kernel<<<2048, 512, 0, stream>>>(g_o, ln_w, ln_b, Wo, out);
}